// Round 5
// baseline (281.307 us; speedup 1.0000x reference)
//
#include <hip/hip_runtime.h>
#include <math.h>

#define BB 32
#define SS 2048
#define EE 128
#define NH 8
#define HDIM 16
#define CACHE_LEN 256
#define SINKS 4
#define WINDOW 128
#define KSEL (SINKS + WINDOW)   // 132
#define ROWS (BB * SS)          // 65536

typedef int v4i __attribute__((ext_vector_type(4)));
typedef short v8s __attribute__((ext_vector_type(8)));
typedef float v4f __attribute__((ext_vector_type(4)));

// workspace layout (bytes)
#define WS_MAXX 0                         // int bits of max|x| (nonneg float as int)
#define WS_MAXO 4                         // int bits of max|attn_out|
#define WS_WS   16                        // float[4] w_scales (q,k,v,o)
#define WS_W(i) (256 + (i) * 16384)       // ternary int8, row-major [o][e]
#define WS_QBUF (256 + 4 * 16384)         // q rows, head-major: [b][h][s][16] f32

// d_out layout: [0, ROWS*128) attn-out then final output (in-place o_proj);
// new_k at ROWS*128, new_v at ROWS*128 + 524288
#define NKV_N (BB * NH * WINDOW * HDIM)   // 524288

// exact fp32 -> bf16 hi/lo split (truncation; f == hi + lo to ~2^-24 rel)
__device__ __forceinline__ uint2 split_bf(float f) {
    unsigned b = __float_as_uint(f);
    unsigned hi = b & 0xffff0000u;
    float lof = f - __uint_as_float(hi);
    return make_uint2(hi >> 16, __float_as_uint(lof) >> 16);
}

// ---- fused weight prep (blocks 0..3) + max|x| (blocks 4..515) -----------
__global__ void prep_and_max(const float* __restrict__ qw, const float* __restrict__ kw,
                             const float* __restrict__ vw, const float* __restrict__ ow,
                             const float* __restrict__ x, char* __restrict__ ws) {
    const int tid = threadIdx.x;
    if (blockIdx.x < 4) {
        const float* W[4] = {qw, kw, vw, ow};
        const int m = blockIdx.x;
        const float* w = W[m];
        __shared__ double red[256];
        double s = 0.0;
        for (int j = tid; j < 16384; j += 256) s += fabs((double)w[j]);
        red[tid] = s;
        __syncthreads();
        for (int st = 128; st > 0; st >>= 1) {
            if (tid < st) red[tid] += red[tid + st];
            __syncthreads();
        }
        const double wscale = red[0] / 16384.0;
        const double thr = 0.5 * wscale;
        if (tid == 0) ((float*)(ws + WS_WS))[m] = (float)wscale;
        signed char* tw = (signed char*)(ws + WS_W(m));
        for (int j = tid; j < 16384; j += 256) {
            const float wv = w[j];
            const double av = fabs((double)wv);
            tw[j] = (av > thr) ? (wv > 0.f ? (signed char)1 : (signed char)-1) : (signed char)0;
        }
    } else {
        __shared__ float red[256];
        float mx = 0.f;
        const int n4 = ROWS * EE / 4;
        const int nthreads = 512 * 256;
        for (int i = (blockIdx.x - 4) * 256 + tid; i < n4; i += nthreads) {
            const float4 v = ((const float4*)x)[i];
            mx = fmaxf(mx, fmaxf(fmaxf(fabsf(v.x), fabsf(v.y)), fmaxf(fabsf(v.z), fabsf(v.w))));
        }
        red[tid] = mx;
        __syncthreads();
        for (int st = 128; st > 0; st >>= 1) {
            if (tid < st) red[tid] = fmaxf(red[tid], red[tid + st]);
            __syncthreads();
        }
        // nonneg float bits as signed int: int-max == float-max; poison (0xAA..) is negative
        if (tid == 0) atomicMax((int*)(ws + WS_MAXX), __float_as_int(red[0]));
    }
}

// ---- int8 MFMA QKV projection -------------------------------------------
__global__ __launch_bounds__(256) void qkv_proj_mfma(const float* __restrict__ x,
                                                     const float* __restrict__ qb,
                                                     const float* __restrict__ kb,
                                                     const float* __restrict__ vb,
                                                     char* __restrict__ ws,
                                                     float* __restrict__ out) {
    const int bx = blockIdx.x;
    const int tid = threadIdx.x;
    int proj, in_row0, b_blk, s0;
    if (bx < 1024) {
        proj = 0; in_row0 = bx * 64; b_blk = bx >> 5; s0 = (bx * 64) & 2047;
    } else {
        int widx = bx - 1024;
        proj = 1 + (widx >> 6);
        widx &= 63;
        b_blk = widx >> 1;
        s0 = (widx & 1) * 64;
        in_row0 = b_blk * 2048 + (SS - WINDOW) + s0;
    }
    const float* bias = (proj == 0) ? qb : (proj == 1) ? kb : vb;
    const signed char* tw = (const signed char*)(ws + WS_W(proj));
    float* dst = (proj == 0) ? (float*)(ws + WS_QBUF)
               : (proj == 1) ? (out + (size_t)ROWS * EE)
                             : (out + (size_t)ROWS * EE + NKV_N);

    const int lane = tid & 63;
    const int wv = tid >> 6;
    const int ml = lane & 15;
    const int quad = lane >> 4;

    v4i bfrag[8][2];
#pragma unroll
    for (int c = 0; c < 8; ++c)
#pragma unroll
        for (int s = 0; s < 2; ++s)
            bfrag[c][s] = *(const v4i*)(tw + (c * 16 + ml) * 128 + s * 64 + quad * 16);

    __shared__ __align__(16) signed char lds_a[64 * 144];
    const float maxx = __int_as_float(*(const int*)(ws + WS_MAXX));
    const float iscale = maxx / 127.0f;
    const float4* x4 = (const float4*)(x + (size_t)in_row0 * 128);
#pragma unroll
    for (int it = 0; it < 8; ++it) {
        const int i = tid + it * 256;
        const int row = i >> 5, c4 = i & 31;
        const float4 v = x4[i];
        float a0 = fminf(fmaxf(rintf(v.x / iscale), -128.f), 127.f);
        float a1 = fminf(fmaxf(rintf(v.y / iscale), -128.f), 127.f);
        float a2 = fminf(fmaxf(rintf(v.z / iscale), -128.f), 127.f);
        float a3 = fminf(fmaxf(rintf(v.w / iscale), -128.f), 127.f);
        const int i0 = (int)a0, i1 = (int)a1, i2 = (int)a2, i3 = (int)a3;
        const int packed = (i0 & 0xff) | ((i1 & 0xff) << 8) | ((i2 & 0xff) << 16) | (i3 << 24);
        *(int*)(lds_a + row * 144 + c4 * 4) = packed;
    }
    __syncthreads();

    const v4i afrag0 = *(const v4i*)(lds_a + (wv * 16 + ml) * 144 + quad * 16);
    const v4i afrag1 = *(const v4i*)(lds_a + (wv * 16 + ml) * 144 + 64 + quad * 16);

    const float wsc = ((const float*)(ws + WS_WS))[proj];
    const float scale = wsc * iscale;

#pragma unroll
    for (int c = 0; c < 8; ++c) {
        v4i acc = {0, 0, 0, 0};
        acc = __builtin_amdgcn_mfma_i32_16x16x64_i8(afrag0, bfrag[c][0], acc, 0, 0, 0);
        acc = __builtin_amdgcn_mfma_i32_16x16x64_i8(afrag1, bfrag[c][1], acc, 0, 0, 0);
        const int col = c * 16 + ml;
        const int h = col >> 4, d = col & 15;
        const float bcol = bias[col];
        const int slen = (proj == 0) ? SS : WINDOW;
#pragma unroll
        for (int r = 0; r < 4; ++r) {
            const int srow = s0 + wv * 16 + quad * 4 + r;
            dst[((size_t)(b_blk * NH + h) * slen + srow) * 16 + d] = (float)acc[r] * scale + bcol;
        }
    }
}

// ---- attention via bf16 MFMA with exact hi/lo split ----------------------
// grid (8, NH, BB), 256 thr = 4 waves; wave w handles q-tiles qchunk*16+w*4..+3
// QK: A=[qh|ql], B1=[kh|kl], B2=[kl|kh] -> 2 MFMAs = exact fp32 product.
// PV: 3 MFMAs per 32-key tile (ph*vh + ph*vl + pl*vh), pl*vl ~2^-18 dropped.
__global__ __launch_bounds__(256, 2) void attention_mfma(const float* __restrict__ ck,
                                                         const float* __restrict__ cv,
                                                         char* __restrict__ ws,
                                                         float* __restrict__ out) {
    const int qchunk = blockIdx.x, h = blockIdx.y, b = blockIdx.z;
    const int tid = threadIdx.x;
    const int lane = tid & 63, w = tid >> 6;
    const int col = lane & 15, quad = lane >> 4;
    const int hb = b * NH + h;

    __shared__ __align__(16) short ksh_hi[144 * 16], ksh_lo[144 * 16];   // [j][d]
    __shared__ __align__(16) short vth[16 * 168], vtl[16 * 168];          // [d][j] pad 160
    __shared__ __align__(16) short pbh[4][16 * 160], pbl[4][16 * 160];    // per-wave P^T [m][j]

    const float* ckh = ck + (size_t)hb * CACHE_LEN * 16;
    const float* cvh = cv + (size_t)hb * CACHE_LEN * 16;
    const float* nkh = out + (size_t)ROWS * EE + (size_t)hb * WINDOW * 16;
    const float* nvh = nkh + NKV_N;

    // stage K ([j][d], rows 132..143 zero) and V transposed ([d][j], cols 132..159 zero)
    for (int idx = tid; idx < 160 * 16; idx += 256) {
        const int j = idx >> 4, d = idx & 15;
        float kf = 0.f, vf = 0.f;
        if (j < SINKS) { kf = ckh[j * 16 + d]; vf = cvh[j * 16 + d]; }
        else if (j < KSEL) { kf = nkh[(j - SINKS) * 16 + d]; vf = nvh[(j - SINKS) * 16 + d]; }
        const uint2 ks = split_bf(kf);
        const uint2 vs = split_bf(vf);
        if (j < 144) { ksh_hi[j * 16 + d] = (short)ks.x; ksh_lo[j * 16 + d] = (short)ks.y; }
        vth[d * 168 + j] = (short)vs.x; vtl[d * 168 + j] = (short)vs.y;
    }
    {   // zero per-wave P pad cols 144..159 (never rewritten)
        short* ph = pbh[w]; short* pl = pbl[w];
        for (int i = lane; i < 256; i += 64) {
            const int r = i >> 4, c = 144 + (i & 15);
            ph[r * 160 + c] = 0; pl[r * 160 + c] = 0;
        }
    }
    __syncthreads();

    // preload K B-frags (per wave): per 16-key tile, 2 variants
    v8s kb1[9], kb2[9];
#pragma unroll
    for (int t = 0; t < 9; ++t) {
        const int jj = t * 16 + col;
        const short* ph_ = ksh_hi + jj * 16 + (quad & 1) * 8;
        const short* pl_ = ksh_lo + jj * 16 + (quad & 1) * 8;
        kb1[t] = *(const v8s*)(quad < 2 ? ph_ : pl_);
        kb2[t] = *(const v8s*)(quad < 2 ? pl_ : ph_);
    }
    // preload V B-frags (per wave): per 32-key tile, hi and lo
    v8s vbh[5], vbl[5];
#pragma unroll
    for (int t = 0; t < 5; ++t) {
        vbh[t] = *(const v8s*)(vth + col * 168 + t * 32 + quad * 8);
        vbl[t] = *(const v8s*)(vtl + col * 168 + t * 32 + quad * 8);
    }

    const float* qbuf = (const float*)(ws + WS_QBUF) + (size_t)hb * SS * 16;
    short* phw = pbh[w];
    short* plw = pbl[w];
    float tmax = 0.f;

    const int qt0 = qchunk * 16 + w * 4;
    const float* qr0 = qbuf + (size_t)(qt0 * 16 + col) * 16 + (quad & 1) * 8;
    float4 nf0 = ((const float4*)qr0)[0];
    float4 nf1 = ((const float4*)qr0)[1];

#pragma unroll 1
    for (int t = 0; t < 4; ++t) {
        const float4 f0 = nf0, f1 = nf1;
        if (t < 3) {
            const float* q2 = qbuf + (size_t)((qt0 + t + 1) * 16 + col) * 16 + (quad & 1) * 8;
            nf0 = ((const float4*)q2)[0];
            nf1 = ((const float4*)q2)[1];
        }
        const int qtile = qt0 + t;
        const int q0 = qtile * 16;

        // A-frag [qh|ql] (0.25 scale folded, exact pow2)
        const float f[8] = {f0.x * 0.25f, f0.y * 0.25f, f0.z * 0.25f, f0.w * 0.25f,
                            f1.x * 0.25f, f1.y * 0.25f, f1.z * 0.25f, f1.w * 0.25f};
        union { unsigned ui[4]; v8s s8; } aq_u;
#pragma unroll
        for (int p = 0; p < 4; ++p) {
            const float e0 = f[2 * p], e1 = f[2 * p + 1];
            const unsigned b0 = __float_as_uint(e0), b1 = __float_as_uint(e1);
            const unsigned hh = (b1 & 0xffff0000u) | (b0 >> 16);
            const float l0 = e0 - __uint_as_float(b0 & 0xffff0000u);
            const float l1 = e1 - __uint_as_float(b1 & 0xffff0000u);
            const unsigned ll = (__float_as_uint(l1) & 0xffff0000u) | (__float_as_uint(l0) >> 16);
            aq_u.ui[p] = (quad < 2) ? hh : ll;
        }
        const v8s aq = aq_u.s8;

        // QK^T: 9 score tiles (C-layout: row=quad*4+r, col=lane&15)
        v4f s[9];
#pragma unroll
        for (int kt = 0; kt < 9; ++kt) {
            v4f z = {0.f, 0.f, 0.f, 0.f};
            z = __builtin_amdgcn_mfma_f32_16x16x32_bf16(aq, kb1[kt], z, 0, 0, 0);
            z = __builtin_amdgcn_mfma_f32_16x16x32_bf16(aq, kb2[kt], z, 0, 0, 0);
            s[kt] = z;
        }

        // masking: causal for qtile<=8; pad cols (j>=132) always
        if (qtile <= 8) {
#pragma unroll
            for (int kt = 0; kt < 9; ++kt) {
                const int j = kt * 16 + col;
#pragma unroll
                for (int r = 0; r < 4; ++r) {
                    const int qi = q0 + quad * 4 + r;
                    const int jl = (qi < KSEL - 1) ? qi : (KSEL - 1);
                    s[kt][r] = (j <= jl) ? s[kt][r] : -INFINITY;
                }
            }
        } else {
#pragma unroll
            for (int r = 0; r < 4; ++r)
                s[8][r] = (col < 4) ? s[8][r] : -INFINITY;
        }

        // row max (within lane over tiles, then across 16 lanes of the quad)
        float mr[4];
#pragma unroll
        for (int r = 0; r < 4; ++r) {
            float mv = s[0][r];
#pragma unroll
            for (int kt = 1; kt < 9; ++kt) mv = fmaxf(mv, s[kt][r]);
            mr[r] = mv;
        }
#pragma unroll
        for (int st = 1; st <= 8; st <<= 1) {
#pragma unroll
            for (int r = 0; r < 4; ++r) mr[r] = fmaxf(mr[r], __shfl_xor(mr[r], st));
        }

        // exp, split, store P^T (hi/lo), accumulate l
        float lr[4] = {0.f, 0.f, 0.f, 0.f};
#pragma unroll
        for (int kt = 0; kt < 9; ++kt) {
#pragma unroll
            for (int r = 0; r < 4; ++r) {
                const float ev = __expf(s[kt][r] - mr[r]);
                lr[r] += ev;
                const unsigned eb = __float_as_uint(ev);
                const unsigned hi = eb & 0xffff0000u;
                const float lof = ev - __uint_as_float(hi);
                const int row = quad * 4 + r, cj = kt * 16 + col;
                phw[row * 160 + cj] = (short)(eb >> 16);
                plw[row * 160 + cj] = (short)(__float_as_uint(lof) >> 16);
            }
        }
#pragma unroll
        for (int st = 1; st <= 8; st <<= 1) {
#pragma unroll
            for (int r = 0; r < 4; ++r) lr[r] += __shfl_xor(lr[r], st);
        }

        // PV: A = P^T rows (m=lane&15), 5 k-tiles of 32 keys
        v4f acc = {0.f, 0.f, 0.f, 0.f};
#pragma unroll
        for (int kt = 0; kt < 5; ++kt) {
            const v8s ph = *(const v8s*)(phw + col * 160 + kt * 32 + quad * 8);
            const v8s pl = *(const v8s*)(plw + col * 160 + kt * 32 + quad * 8);
            acc = __builtin_amdgcn_mfma_f32_16x16x32_bf16(ph, vbh[kt], acc, 0, 0, 0);
            acc = __builtin_amdgcn_mfma_f32_16x16x32_bf16(ph, vbl[kt], acc, 0, 0, 0);
            acc = __builtin_amdgcn_mfma_f32_16x16x32_bf16(pl, vbh[kt], acc, 0, 0, 0);
        }

        // epilogue: normalize, track max|.|, store (C-layout: row=query, col=d)
#pragma unroll
        for (int r = 0; r < 4; ++r) {
            const int qi = q0 + quad * 4 + r;
            const float val = acc[r] / lr[r];
            tmax = fmaxf(tmax, fabsf(val));
            out[(size_t)(b * SS + qi) * 128 + h * 16 + col] = val;
        }
    }

#pragma unroll
    for (int st = 1; st <= 32; st <<= 1) tmax = fmaxf(tmax, __shfl_xor(tmax, st));
    if (lane == 0) atomicMax((int*)(ws + WS_MAXO), __float_as_int(tmax));
}

// ---- O projection, int8 MFMA, in-place on d_out -------------------------
__global__ __launch_bounds__(256) void o_proj_mfma(const float* __restrict__ ob,
                                                   char* __restrict__ ws,
                                                   float* __restrict__ out) {
    const int bx = blockIdx.x;
    const int tid = threadIdx.x;
    const int in_row0 = bx * 64;
    const signed char* tw = (const signed char*)(ws + WS_W(3));

    const int lane = tid & 63;
    const int wv = tid >> 6;
    const int ml = lane & 15;
    const int quad = lane >> 4;

    v4i bfrag[8][2];
#pragma unroll
    for (int c = 0; c < 8; ++c)
#pragma unroll
        for (int s = 0; s < 2; ++s)
            bfrag[c][s] = *(const v4i*)(tw + (c * 16 + ml) * 128 + s * 64 + quad * 16);

    __shared__ __align__(16) signed char lds_a[64 * 144];
    const float maxo = __int_as_float(*(const int*)(ws + WS_MAXO));
    const float iscale = maxo / 127.0f;
    const float4* x4 = (const float4*)(out + (size_t)in_row0 * 128);
#pragma unroll
    for (int it = 0; it < 8; ++it) {
        const int i = tid + it * 256;
        const int row = i >> 5, c4 = i & 31;
        const float4 v = x4[i];
        float a0 = fminf(fmaxf(rintf(v.x / iscale), -128.f), 127.f);
        float a1 = fminf(fmaxf(rintf(v.y / iscale), -128.f), 127.f);
        float a2 = fminf(fmaxf(rintf(v.z / iscale), -128.f), 127.f);
        float a3 = fminf(fmaxf(rintf(v.w / iscale), -128.f), 127.f);
        const int i0 = (int)a0, i1 = (int)a1, i2 = (int)a2, i3 = (int)a3;
        const int packed = (i0 & 0xff) | ((i1 & 0xff) << 8) | ((i2 & 0xff) << 16) | (i3 << 24);
        *(int*)(lds_a + row * 144 + c4 * 4) = packed;
    }
    __syncthreads();

    const v4i afrag0 = *(const v4i*)(lds_a + (wv * 16 + ml) * 144 + quad * 16);
    const v4i afrag1 = *(const v4i*)(lds_a + (wv * 16 + ml) * 144 + 64 + quad * 16);

    const float wsc = ((const float*)(ws + WS_WS))[3];
    const float scale = wsc * iscale;

#pragma unroll
    for (int c = 0; c < 8; ++c) {
        v4i acc = {0, 0, 0, 0};
        acc = __builtin_amdgcn_mfma_i32_16x16x64_i8(afrag0, bfrag[c][0], acc, 0, 0, 0);
        acc = __builtin_amdgcn_mfma_i32_16x16x64_i8(afrag1, bfrag[c][1], acc, 0, 0, 0);
        const int col = c * 16 + ml;
        const float bcol = ob[col];
#pragma unroll
        for (int r = 0; r < 4; ++r) {
            const int row = wv * 16 + quad * 4 + r;
            out[(size_t)(in_row0 + row) * 128 + col] = (float)acc[r] * scale + bcol;
        }
    }
}

extern "C" void kernel_launch(void* const* d_in, const int* in_sizes, int n_in,
                              void* d_out, int out_size, void* d_ws, size_t ws_size,
                              hipStream_t stream) {
    const float* x  = (const float*)d_in[0];
    const float* ck = (const float*)d_in[1];
    const float* cv = (const float*)d_in[2];
    const float* qw = (const float*)d_in[3];
    const float* qb = (const float*)d_in[4];
    const float* kw = (const float*)d_in[5];
    const float* kb = (const float*)d_in[6];
    const float* vw = (const float*)d_in[7];
    const float* vb = (const float*)d_in[8];
    const float* ow = (const float*)d_in[9];
    const float* ob = (const float*)d_in[10];
    char* ws = (char*)d_ws;
    float* out = (float*)d_out;

    prep_and_max<<<4 + 512, 256, 0, stream>>>(qw, kw, vw, ow, x, ws);
    qkv_proj_mfma<<<1024 + 128, 256, 0, stream>>>(x, qb, kb, vb, ws, out);
    attention_mfma<<<dim3(8, NH, BB), 256, 0, stream>>>(ck, cv, ws, out);
    o_proj_mfma<<<1024, 256, 0, stream>>>(ob, ws, out);
}

// Round 6
// 264.882 us; speedup vs baseline: 1.0620x; 1.0620x over previous
//
#include <hip/hip_runtime.h>
#include <math.h>

#define BB 32
#define SS 2048
#define EE 128
#define NH 8
#define HDIM 16
#define CACHE_LEN 256
#define SINKS 4
#define WINDOW 128
#define KSEL (SINKS + WINDOW)   // 132
#define ROWS (BB * SS)          // 65536

typedef int v4i __attribute__((ext_vector_type(4)));
typedef short v8s __attribute__((ext_vector_type(8)));
typedef float v4f __attribute__((ext_vector_type(4)));

// workspace layout (bytes)
#define WS_MAXX 0                         // int bits of max|x| (nonneg float as int)
#define WS_MAXO 4                         // int bits of max|attn_out|
#define WS_WS   16                        // float[4] w_scales (q,k,v,o)
#define WS_W(i) (256 + (i) * 16384)       // ternary int8, row-major [o][e]
#define WS_QBUF (256 + 4 * 16384)         // q rows, head-major: [b][h][s][16] f32

// d_out layout: [0, ROWS*128) attn-out then final output (in-place o_proj);
// new_k at ROWS*128, new_v at ROWS*128 + 524288
#define NKV_N (BB * NH * WINDOW * HDIM)   // 524288

// ---- fused weight prep (blocks 0..3) + max|x| (blocks 4..515) -----------
__global__ void prep_and_max(const float* __restrict__ qw, const float* __restrict__ kw,
                             const float* __restrict__ vw, const float* __restrict__ ow,
                             const float* __restrict__ x, char* __restrict__ ws) {
    const int tid = threadIdx.x;
    if (blockIdx.x < 4) {
        const float* W[4] = {qw, kw, vw, ow};
        const int m = blockIdx.x;
        const float* w = W[m];
        __shared__ double red[256];
        double s = 0.0;
        for (int j = tid; j < 16384; j += 256) s += fabs((double)w[j]);
        red[tid] = s;
        __syncthreads();
        for (int st = 128; st > 0; st >>= 1) {
            if (tid < st) red[tid] += red[tid + st];
            __syncthreads();
        }
        const double wscale = red[0] / 16384.0;
        const double thr = 0.5 * wscale;
        if (tid == 0) ((float*)(ws + WS_WS))[m] = (float)wscale;
        signed char* tw = (signed char*)(ws + WS_W(m));
        for (int j = tid; j < 16384; j += 256) {
            const float wv = w[j];
            const double av = fabs((double)wv);
            tw[j] = (av > thr) ? (wv > 0.f ? (signed char)1 : (signed char)-1) : (signed char)0;
        }
    } else {
        __shared__ float red[256];
        float mx = 0.f;
        const int n4 = ROWS * EE / 4;
        const int nthreads = 512 * 256;
        for (int i = (blockIdx.x - 4) * 256 + tid; i < n4; i += nthreads) {
            const float4 v = ((const float4*)x)[i];
            mx = fmaxf(mx, fmaxf(fmaxf(fabsf(v.x), fabsf(v.y)), fmaxf(fabsf(v.z), fabsf(v.w))));
        }
        red[tid] = mx;
        __syncthreads();
        for (int st = 128; st > 0; st >>= 1) {
            if (tid < st) red[tid] = fmaxf(red[tid], red[tid + st]);
            __syncthreads();
        }
        if (tid == 0) atomicMax((int*)(ws + WS_MAXX), __float_as_int(red[0]));
    }
}

// ---- int8 MFMA QKV projection -------------------------------------------
__global__ __launch_bounds__(256) void qkv_proj_mfma(const float* __restrict__ x,
                                                     const float* __restrict__ qb,
                                                     const float* __restrict__ kb,
                                                     const float* __restrict__ vb,
                                                     char* __restrict__ ws,
                                                     float* __restrict__ out) {
    const int bx = blockIdx.x;
    const int tid = threadIdx.x;
    int proj, in_row0, b_blk, s0;
    if (bx < 1024) {
        proj = 0; in_row0 = bx * 64; b_blk = bx >> 5; s0 = (bx * 64) & 2047;
    } else {
        int widx = bx - 1024;
        proj = 1 + (widx >> 6);
        widx &= 63;
        b_blk = widx >> 1;
        s0 = (widx & 1) * 64;
        in_row0 = b_blk * 2048 + (SS - WINDOW) + s0;
    }
    const float* bias = (proj == 0) ? qb : (proj == 1) ? kb : vb;
    const signed char* tw = (const signed char*)(ws + WS_W(proj));
    float* dst = (proj == 0) ? (float*)(ws + WS_QBUF)
               : (proj == 1) ? (out + (size_t)ROWS * EE)
                             : (out + (size_t)ROWS * EE + NKV_N);

    const int lane = tid & 63;
    const int wv = tid >> 6;
    const int ml = lane & 15;
    const int quad = lane >> 4;

    v4i bfrag[8][2];
#pragma unroll
    for (int c = 0; c < 8; ++c)
#pragma unroll
        for (int s = 0; s < 2; ++s)
            bfrag[c][s] = *(const v4i*)(tw + (c * 16 + ml) * 128 + s * 64 + quad * 16);

    __shared__ __align__(16) signed char lds_a[64 * 144];
    const float maxx = __int_as_float(*(const int*)(ws + WS_MAXX));
    const float iscale = maxx / 127.0f;
    const float4* x4 = (const float4*)(x + (size_t)in_row0 * 128);
#pragma unroll
    for (int it = 0; it < 8; ++it) {
        const int i = tid + it * 256;
        const int row = i >> 5, c4 = i & 31;
        const float4 v = x4[i];
        float a0 = fminf(fmaxf(rintf(v.x / iscale), -128.f), 127.f);
        float a1 = fminf(fmaxf(rintf(v.y / iscale), -128.f), 127.f);
        float a2 = fminf(fmaxf(rintf(v.z / iscale), -128.f), 127.f);
        float a3 = fminf(fmaxf(rintf(v.w / iscale), -128.f), 127.f);
        const int i0 = (int)a0, i1 = (int)a1, i2 = (int)a2, i3 = (int)a3;
        const int packed = (i0 & 0xff) | ((i1 & 0xff) << 8) | ((i2 & 0xff) << 16) | (i3 << 24);
        *(int*)(lds_a + row * 144 + c4 * 4) = packed;
    }
    __syncthreads();

    const v4i afrag0 = *(const v4i*)(lds_a + (wv * 16 + ml) * 144 + quad * 16);
    const v4i afrag1 = *(const v4i*)(lds_a + (wv * 16 + ml) * 144 + 64 + quad * 16);

    const float wsc = ((const float*)(ws + WS_WS))[proj];
    const float scale = wsc * iscale;

#pragma unroll
    for (int c = 0; c < 8; ++c) {
        v4i acc = {0, 0, 0, 0};
        acc = __builtin_amdgcn_mfma_i32_16x16x64_i8(afrag0, bfrag[c][0], acc, 0, 0, 0);
        acc = __builtin_amdgcn_mfma_i32_16x16x64_i8(afrag1, bfrag[c][1], acc, 0, 0, 0);
        const int col = c * 16 + ml;
        const int h = col >> 4, d = col & 15;
        const float bcol = bias[col];
        const int slen = (proj == 0) ? SS : WINDOW;
#pragma unroll
        for (int r = 0; r < 4; ++r) {
            const int srow = s0 + wv * 16 + quad * 4 + r;
            dst[((size_t)(b_blk * NH + h) * slen + srow) * 16 + d] = (float)acc[r] * scale + bcol;
        }
    }
}

// ---- attention: S^T formulation, zero LDS, bpermute P relayout ----------
// S^T = K.Q^T via 2 exact MFMAs (hh+ll then hl+lh). C-layout: lane holds
// query col=lane&15, keys=quad*4+r (+16t). Softmax per query col: 2 shfl_xor.
// O^T = V^T.P^T: B-frags of P^T built by ds_bpermute from the C-layout regs.
__global__ __launch_bounds__(256, 3) void attention_mfma(const float* __restrict__ ck,
                                                         const float* __restrict__ cv,
                                                         char* __restrict__ ws,
                                                         float* __restrict__ out) {
    const int qx = blockIdx.x, h = blockIdx.y, b = blockIdx.z;
    const int tid = threadIdx.x;
    const int lane = tid & 63, w = tid >> 6;
    const int col = lane & 15, quad = lane >> 4;
    const int hb = b * NH + h;
    const int dof = (quad & 1) * 8;

    const float* ckh = ck + (size_t)hb * CACHE_LEN * 16;
    const float* cvh = cv + (size_t)hb * CACHE_LEN * 16;
    const float* nkh = out + (size_t)ROWS * EE + (size_t)hb * WINDOW * 16;
    const float* nvh = nkh + NKV_N;
    const float* qbuf = (const float*)(ws + WS_QBUF) + (size_t)hb * SS * 16;

    // --- K A-frags: ka[t] = [kh|kl] over k=quad*8+j (d = dof+j) ---
    v8s ka[9];
#pragma unroll
    for (int t = 0; t < 9; ++t) {
        const int j = t * 16 + col;
        float4 f0 = make_float4(0.f, 0.f, 0.f, 0.f), f1 = f0;
        if (j < KSEL) {
            const float* kr = (j < SINKS) ? (ckh + j * 16 + dof) : (nkh + (j - SINKS) * 16 + dof);
            f0 = ((const float4*)kr)[0];
            f1 = ((const float4*)kr)[1];
        }
        const float fl[8] = {f0.x, f0.y, f0.z, f0.w, f1.x, f1.y, f1.z, f1.w};
        unsigned hb_[8], lb_[8];
#pragma unroll
        for (int i = 0; i < 8; ++i) {
            const unsigned bb = __float_as_uint(fl[i]);
            hb_[i] = bb;
            lb_[i] = __float_as_uint(fl[i] - __uint_as_float(bb & 0xffff0000u));
        }
        union { v8s s; unsigned u[4]; } H, L;
#pragma unroll
        for (int p = 0; p < 4; ++p) {
            H.u[p] = __builtin_amdgcn_perm(hb_[2 * p + 1], hb_[2 * p], 0x07060302);
            L.u[p] = __builtin_amdgcn_perm(lb_[2 * p + 1], lb_[2 * p], 0x07060302);
        }
        ka[t] = (quad < 2) ? H.s : L.s;
    }

    // --- V^T A-frags (hi and lo): m=d=col, k=key=32c+quad*8+j ---
    v8s vah[5], val[5];
#pragma unroll
    for (int c = 0; c < 5; ++c) {
        float fv[8];
#pragma unroll
        for (int j = 0; j < 8; ++j) {
            const int key = c * 32 + quad * 8 + j;
            float v = 0.f;
            if (key < SINKS) v = cvh[key * 16 + col];
            else if (key < KSEL) v = nvh[(key - SINKS) * 16 + col];
            fv[j] = v;
        }
        unsigned hb_[8], lb_[8];
#pragma unroll
        for (int i = 0; i < 8; ++i) {
            const unsigned bb = __float_as_uint(fv[i]);
            hb_[i] = bb;
            lb_[i] = __float_as_uint(fv[i] - __uint_as_float(bb & 0xffff0000u));
        }
        union { v8s s; unsigned u[4]; } H, L;
#pragma unroll
        for (int p = 0; p < 4; ++p) {
            H.u[p] = __builtin_amdgcn_perm(hb_[2 * p + 1], hb_[2 * p], 0x07060302);
            L.u[p] = __builtin_amdgcn_perm(lb_[2 * p + 1], lb_[2 * p], 0x07060302);
        }
        vah[c] = H.s;
        val[c] = L.s;
    }

    const int idxA = (((quad & 1) * 32) + col) * 4;   // src lane sq=(quad&1)*2, same col
    const int idxB = idxA + 64;                       // sq+1
    float tmax = 0.f;

#pragma unroll 1
    for (int t = 0; t < 4; ++t) {
        const int qbase = qx * 256 + (w * 4 + t) * 16;

        // Q B-frags (scale 0.25 folded; exact pow2)
        const float* qr = qbuf + (size_t)(qbase + col) * 16 + dof;
        float4 f0 = ((const float4*)qr)[0];
        float4 f1 = ((const float4*)qr)[1];
        const float fl[8] = {f0.x * 0.25f, f0.y * 0.25f, f0.z * 0.25f, f0.w * 0.25f,
                             f1.x * 0.25f, f1.y * 0.25f, f1.z * 0.25f, f1.w * 0.25f};
        unsigned hb_[8], lb_[8];
#pragma unroll
        for (int i = 0; i < 8; ++i) {
            const unsigned bb = __float_as_uint(fl[i]);
            hb_[i] = bb;
            lb_[i] = __float_as_uint(fl[i] - __uint_as_float(bb & 0xffff0000u));
        }
        union { v8s s; unsigned u[4]; } H, L;
#pragma unroll
        for (int p = 0; p < 4; ++p) {
            H.u[p] = __builtin_amdgcn_perm(hb_[2 * p + 1], hb_[2 * p], 0x07060302);
            L.u[p] = __builtin_amdgcn_perm(lb_[2 * p + 1], lb_[2 * p], 0x07060302);
        }
        const v8s B1 = (quad < 2) ? H.s : L.s;   // [qh|ql]
        const v8s B2 = (quad < 2) ? L.s : H.s;   // [ql|qh]

        // S^T tiles
        v4f S[9];
#pragma unroll
        for (int kt = 0; kt < 9; ++kt) {
            v4f z = {0.f, 0.f, 0.f, 0.f};
            z = __builtin_amdgcn_mfma_f32_16x16x32_bf16(ka[kt], B1, z, 0, 0, 0);
            z = __builtin_amdgcn_mfma_f32_16x16x32_bf16(ka[kt], B2, z, 0, 0, 0);
            S[kt] = z;
        }

        // masking (key j = 16kt + 4*quad + r; query qi = qbase+col)
        if (qx == 0) {
            const int qi = qbase + col;
            const int jmax = (qi < KSEL - 1) ? qi : (KSEL - 1);
            const int q4 = quad * 4;
#pragma unroll
            for (int kt = 0; kt < 9; ++kt)
#pragma unroll
                for (int r = 0; r < 4; ++r)
                    S[kt][r] = (kt * 16 + q4 + r <= jmax) ? S[kt][r] : -INFINITY;
        } else {
#pragma unroll
            for (int r = 0; r < 4; ++r)
                S[8][r] = (quad == 0) ? S[8][r] : -INFINITY;
        }

        // per-query max (in-lane 36, then across quads)
        float mr = S[0][0];
#pragma unroll
        for (int kt = 0; kt < 9; ++kt)
#pragma unroll
            for (int r = 0; r < 4; ++r) mr = fmaxf(mr, S[kt][r]);
        mr = fmaxf(mr, __shfl_xor(mr, 16));
        mr = fmaxf(mr, __shfl_xor(mr, 32));

        // exp + hi/lo pack + PV, chunked (tiles 2c, 2c+1 -> 32-key chunk c)
        float lsum = 0.f;
        v4f acc = {0.f, 0.f, 0.f, 0.f};
#pragma unroll
        for (int c = 0; c < 5; ++c) {
            int P0[4], P1[4];
#pragma unroll
            for (int r = 0; r < 4; ++r) {
                const float e = __expf(S[2 * c][r] - mr);
                lsum += e;
                const unsigned eb = __float_as_uint(e);
                const unsigned hi = eb & 0xffff0000u;
                const float lf = e - __uint_as_float(hi);
                P0[r] = (int)(hi | (__float_as_uint(lf) >> 16));
            }
            if (c < 4) {
#pragma unroll
                for (int r = 0; r < 4; ++r) {
                    const float e = __expf(S[2 * c + 1][r] - mr);
                    lsum += e;
                    const unsigned eb = __float_as_uint(e);
                    const unsigned hi = eb & 0xffff0000u;
                    const float lf = e - __uint_as_float(hi);
                    P1[r] = (int)(hi | (__float_as_uint(lf) >> 16));
                }
            }
            // B-frag relayout: dst reg j (key quad*8+j): src lane sq*16+col
            int pj[8];
#pragma unroll
            for (int j = 0; j < 8; ++j) {
                const int idx = (j < 4) ? idxA : idxB;
                const int lo_ = __builtin_amdgcn_ds_bpermute(idx, P0[j & 3]);
                const int hi_ = (c < 4) ? __builtin_amdgcn_ds_bpermute(idx, P1[j & 3]) : 0;
                pj[j] = (quad < 2) ? lo_ : hi_;
            }
            union { v8s s; unsigned u[4]; } BH, BL;
#pragma unroll
            for (int p = 0; p < 4; ++p) {
                BH.u[p] = __builtin_amdgcn_perm((unsigned)pj[2 * p + 1], (unsigned)pj[2 * p], 0x07060302);
                BL.u[p] = __builtin_amdgcn_perm((unsigned)pj[2 * p + 1], (unsigned)pj[2 * p], 0x05040100);
            }
            acc = __builtin_amdgcn_mfma_f32_16x16x32_bf16(vah[c], BH.s, acc, 0, 0, 0);
            acc = __builtin_amdgcn_mfma_f32_16x16x32_bf16(val[c], BH.s, acc, 0, 0, 0);
            acc = __builtin_amdgcn_mfma_f32_16x16x32_bf16(vah[c], BL.s, acc, 0, 0, 0);
        }
        lsum += __shfl_xor(lsum, 16);
        lsum += __shfl_xor(lsum, 32);

        // epilogue: O^T C-layout -> lane holds O[query=col][d=quad*4+r]
        const float inv = 1.0f / lsum;
        float4 ov;
        ov.x = acc[0] * inv; ov.y = acc[1] * inv;
        ov.z = acc[2] * inv; ov.w = acc[3] * inv;
        tmax = fmaxf(tmax, fmaxf(fmaxf(fabsf(ov.x), fabsf(ov.y)), fmaxf(fabsf(ov.z), fabsf(ov.w))));
        *(float4*)(out + (size_t)(b * SS + qbase + col) * 128 + h * 16 + quad * 4) = ov;
    }

#pragma unroll
    for (int st = 1; st <= 32; st <<= 1) tmax = fmaxf(tmax, __shfl_xor(tmax, st));
    if (lane == 0) atomicMax((int*)(ws + WS_MAXO), __float_as_int(tmax));
}

// ---- O projection, int8 MFMA, in-place on d_out -------------------------
__global__ __launch_bounds__(256) void o_proj_mfma(const float* __restrict__ ob,
                                                   char* __restrict__ ws,
                                                   float* __restrict__ out) {
    const int bx = blockIdx.x;
    const int tid = threadIdx.x;
    const int in_row0 = bx * 64;
    const signed char* tw = (const signed char*)(ws + WS_W(3));

    const int lane = tid & 63;
    const int wv = tid >> 6;
    const int ml = lane & 15;
    const int quad = lane >> 4;

    v4i bfrag[8][2];
#pragma unroll
    for (int c = 0; c < 8; ++c)
#pragma unroll
        for (int s = 0; s < 2; ++s)
            bfrag[c][s] = *(const v4i*)(tw + (c * 16 + ml) * 128 + s * 64 + quad * 16);

    __shared__ __align__(16) signed char lds_a[64 * 144];
    const float maxo = __int_as_float(*(const int*)(ws + WS_MAXO));
    const float iscale = maxo / 127.0f;
    const float4* x4 = (const float4*)(out + (size_t)in_row0 * 128);
#pragma unroll
    for (int it = 0; it < 8; ++it) {
        const int i = tid + it * 256;
        const int row = i >> 5, c4 = i & 31;
        const float4 v = x4[i];
        float a0 = fminf(fmaxf(rintf(v.x / iscale), -128.f), 127.f);
        float a1 = fminf(fmaxf(rintf(v.y / iscale), -128.f), 127.f);
        float a2 = fminf(fmaxf(rintf(v.z / iscale), -128.f), 127.f);
        float a3 = fminf(fmaxf(rintf(v.w / iscale), -128.f), 127.f);
        const int i0 = (int)a0, i1 = (int)a1, i2 = (int)a2, i3 = (int)a3;
        const int packed = (i0 & 0xff) | ((i1 & 0xff) << 8) | ((i2 & 0xff) << 16) | (i3 << 24);
        *(int*)(lds_a + row * 144 + c4 * 4) = packed;
    }
    __syncthreads();

    const v4i afrag0 = *(const v4i*)(lds_a + (wv * 16 + ml) * 144 + quad * 16);
    const v4i afrag1 = *(const v4i*)(lds_a + (wv * 16 + ml) * 144 + 64 + quad * 16);

    const float wsc = ((const float*)(ws + WS_WS))[3];
    const float scale = wsc * iscale;

#pragma unroll
    for (int c = 0; c < 8; ++c) {
        v4i acc = {0, 0, 0, 0};
        acc = __builtin_amdgcn_mfma_i32_16x16x64_i8(afrag0, bfrag[c][0], acc, 0, 0, 0);
        acc = __builtin_amdgcn_mfma_i32_16x16x64_i8(afrag1, bfrag[c][1], acc, 0, 0, 0);
        const int col = c * 16 + ml;
        const float bcol = ob[col];
#pragma unroll
        for (int r = 0; r < 4; ++r) {
            const int row = wv * 16 + quad * 4 + r;
            out[(size_t)(in_row0 + row) * 128 + col] = (float)acc[r] * scale + bcol;
        }
    }
}

extern "C" void kernel_launch(void* const* d_in, const int* in_sizes, int n_in,
                              void* d_out, int out_size, void* d_ws, size_t ws_size,
                              hipStream_t stream) {
    const float* x  = (const float*)d_in[0];
    const float* ck = (const float*)d_in[1];
    const float* cv = (const float*)d_in[2];
    const float* qw = (const float*)d_in[3];
    const float* qb = (const float*)d_in[4];
    const float* kw = (const float*)d_in[5];
    const float* kb = (const float*)d_in[6];
    const float* vw = (const float*)d_in[7];
    const float* vb = (const float*)d_in[8];
    const float* ow = (const float*)d_in[9];
    const float* ob = (const float*)d_in[10];
    char* ws = (char*)d_ws;
    float* out = (float*)d_out;

    prep_and_max<<<4 + 512, 256, 0, stream>>>(qw, kw, vw, ow, x, ws);
    qkv_proj_mfma<<<1024 + 128, 256, 0, stream>>>(x, qb, kb, vb, ws, out);
    attention_mfma<<<dim3(8, NH, BB), 256, 0, stream>>>(ck, cv, ws, out);
    o_proj_mfma<<<1024, 256, 0, stream>>>(ob, ws, out);
}